// Round 6
// baseline (201.846 us; speedup 1.0000x reference)
//
#include <hip/hip_runtime.h>
#include <stdint.h>

#define N_NODES 100000
#define N_EDGES 1600000
#define IN_DIM 128
#define OUT_DIM 64

typedef __bf16    bf16x8 __attribute__((ext_vector_type(8)));
typedef float     f32x4  __attribute__((ext_vector_type(4)));
typedef _Float16  h2     __attribute__((ext_vector_type(2)));

__device__ __forceinline__ uint16_t f2bf(float f) {   // RNE
    uint32_t u = __float_as_uint(f);
    return (uint16_t)((u + 0x7fffu + ((u >> 16) & 1u)) >> 16);
}
__device__ __forceinline__ int dot4i8(uint32_t a, uint32_t b, int c) {
#if __has_builtin(__builtin_amdgcn_sdot4)
    return __builtin_amdgcn_sdot4((int)a, (int)b, c, false);
#else
    #pragma unroll
    for (int k = 0; k < 4; ++k)
        c += (int)(int8_t)(a >> (8 * k)) * (int)(int8_t)(b >> (8 * k));
    return c;
#endif
}
__device__ __forceinline__ float hdot8(uint4 a, uint4 b, float c) {
#if __has_builtin(__builtin_amdgcn_fdot2)
    c = __builtin_amdgcn_fdot2(__builtin_bit_cast(h2, a.x), __builtin_bit_cast(h2, b.x), c, false);
    c = __builtin_amdgcn_fdot2(__builtin_bit_cast(h2, a.y), __builtin_bit_cast(h2, b.y), c, false);
    c = __builtin_amdgcn_fdot2(__builtin_bit_cast(h2, a.z), __builtin_bit_cast(h2, b.z), c, false);
    c = __builtin_amdgcn_fdot2(__builtin_bit_cast(h2, a.w), __builtin_bit_cast(h2, b.w), c, false);
#else
    const h2 qa[4] = {__builtin_bit_cast(h2,a.x),__builtin_bit_cast(h2,a.y),
                      __builtin_bit_cast(h2,a.z),__builtin_bit_cast(h2,a.w)};
    const h2 qb[4] = {__builtin_bit_cast(h2,b.x),__builtin_bit_cast(h2,b.y),
                      __builtin_bit_cast(h2,b.z),__builtin_bit_cast(h2,b.w)};
    #pragma unroll
    for (int i = 0; i < 4; ++i) {
        c = fmaf((float)qa[i][0], (float)qb[i][0], c);
        c = fmaf((float)qa[i][1], (float)qb[i][1], c);
    }
#endif
    return c;
}

// ---------------------------------------------------------------------------
// prep: blocks [0,6250) build row_ptr from sorted edge_src (O(N+E));
//       blocks [6250,6254) pack W into per-lane MFMA B-fragments + zero gmax.
// ---------------------------------------------------------------------------
__global__ __launch_bounds__(256) void prep(const int* __restrict__ src,
                                            const float* __restrict__ W,
                                            int* __restrict__ row_ptr,
                                            uint4* __restrict__ Wfrag,
                                            unsigned* __restrict__ gmax) {
    const int b = blockIdx.x;
    if (b < N_EDGES / 256) {
        int e = b * 256 + threadIdx.x;
        int s = src[e];
        if (e == 0) {
            for (int i = 0; i <= s; ++i) row_ptr[i] = 0;
        } else {
            int sp = src[e - 1];
            for (int i = sp + 1; i <= s; ++i) row_ptr[i] = e;
        }
        if (e == N_EDGES - 1) {
            for (int i = s + 1; i <= N_NODES; ++i) row_ptr[i] = N_EDGES;
        }
    } else {
        if (b == N_EDGES / 256 && threadIdx.x == 0) *gmax = 0u;
        int item = (b - N_EDGES / 256) * 256 + threadIdx.x;   // 0..1023
        if (item < 1024) {
            int f = item >> 6, lane = item & 63;
            int ct = f >> 2, ks = f & 3;
            int col = ct * 16 + (lane & 15);
            int kb  = ks * 32 + (lane >> 4) * 8;
            uint32_t u[4];
            #pragma unroll
            for (int j = 0; j < 4; ++j) {
                uint32_t lo = f2bf(W[(kb + 2 * j)     * OUT_DIM + col]);
                uint32_t hi = f2bf(W[(kb + 2 * j + 1) * OUT_DIM + col]);
                u[j] = lo | (hi << 16);
            }
            Wfrag[f * 64 + lane] = make_uint4(u[0], u[1], u[2], u[3]);
        }
    }
}

// ---------------------------------------------------------------------------
// GEMM: XPh = f16(X @ W) via mfma_f32_16x16x32_bf16; also wave-reduce
// max|acc| -> atomicMax(gmax) (order-independent => deterministic).
// ---------------------------------------------------------------------------
__global__ __launch_bounds__(256) void gemm_xw(const float* __restrict__ X,
                                               const uint4* __restrict__ Wfrag,
                                               _Float16* __restrict__ XPh,
                                               unsigned* __restrict__ gmax,
                                               int nRows) {
    const int t = threadIdx.x;
    const int lane = t & 63;

    bf16x8 bfr[16];
    #pragma unroll
    for (int f = 0; f < 16; ++f)
        bfr[f] = __builtin_bit_cast(bf16x8, Wfrag[f * 64 + lane]);

    const int rowBase = blockIdx.x * 64 + (t >> 6) * 16;
    const int r  = rowBase + (lane & 15);
    const int kb = (lane >> 4) * 8;
    const bool inb = r < nRows;

    f32x4 acc[4] = {{0,0,0,0},{0,0,0,0},{0,0,0,0},{0,0,0,0}};

    #pragma unroll
    for (int ks = 0; ks < 4; ++ks) {
        float4 x0 = make_float4(0.f,0.f,0.f,0.f), x1 = x0;
        if (inb) {
            const float* p = &X[(size_t)r * IN_DIM + ks * 32 + kb];
            x0 = *(const float4*)&p[0];
            x1 = *(const float4*)&p[4];
        }
        bf16x8 a;
        a[0]=(__bf16)x0.x; a[1]=(__bf16)x0.y; a[2]=(__bf16)x0.z; a[3]=(__bf16)x0.w;
        a[4]=(__bf16)x1.x; a[5]=(__bf16)x1.y; a[6]=(__bf16)x1.z; a[7]=(__bf16)x1.w;
        #pragma unroll
        for (int ct = 0; ct < 4; ++ct)
            acc[ct] = __builtin_amdgcn_mfma_f32_16x16x32_bf16(a, bfr[ct * 4 + ks], acc[ct], 0, 0, 0);
    }

    const int orow = rowBase + (lane >> 4) * 4;
    const int ocol = lane & 15;
    float m = 0.f;
    #pragma unroll
    for (int ct = 0; ct < 4; ++ct) {
        #pragma unroll
        for (int rr = 0; rr < 4; ++rr) {
            int gr = orow + rr;
            if (gr < nRows) XPh[(size_t)gr * OUT_DIM + ct * 16 + ocol] = (_Float16)acc[ct][rr];
            m = fmaxf(m, fabsf(acc[ct][rr]));
        }
    }
    #pragma unroll
    for (int off = 1; off < 64; off <<= 1) m = fmaxf(m, __shfl_xor(m, off));
    if (lane == 0) atomicMax(gmax, __float_as_uint(m));
}

// ---------------------------------------------------------------------------
// quantize: Q[i] = int8(rint(XPh[i] * 127/gmax)). 8 elems/thread.
// ---------------------------------------------------------------------------
__global__ __launch_bounds__(256) void quantize(const _Float16* __restrict__ XPh,
                                                const unsigned* __restrict__ gmax,
                                                uint2* __restrict__ Q) {
    const int i = blockIdx.x * 256 + threadIdx.x;        // 800000 threads
    const float gm = __uint_as_float(*gmax);
    const float inv = gm > 0.f ? 127.f / gm : 0.f;
    uint4 h = ((const uint4*)XPh)[i];
    uint32_t w[2];
    #pragma unroll
    for (int half = 0; half < 2; ++half) {
        uint32_t res = 0;
        #pragma unroll
        for (int j = 0; j < 2; ++j) {
            uint32_t hw = half == 0 ? (j == 0 ? h.x : h.y) : (j == 0 ? h.z : h.w);
            h2 p = __builtin_bit_cast(h2, hw);
            int v0 = (int)rintf((float)p[0] * inv);
            int v1 = (int)rintf((float)p[1] * inv);
            res |= ((uint32_t)(uint8_t)(int8_t)v0) << (j * 16);
            res |= ((uint32_t)(uint8_t)(int8_t)v1) << (j * 16 + 8);
        }
        w[half] = res;
    }
    Q[i] = make_uint2(w[0], w[1]);
}

// ---------------------------------------------------------------------------
// Edge kernel (int8): one NODE per 8-lane group; row = 64B = ONE cache line
// (8B/lane). Depth-2 software pipeline. acc accumulates exact int products
// p_int*q_j in f32; single final scale by (gmax/127)^3 * aw.
// ---------------------------------------------------------------------------
__global__ __launch_bounds__(256, 8) void agnn_edge_q(const uint8_t* __restrict__ Q,
                                                      const int* __restrict__ row_ptr,
                                                      const int* __restrict__ dst,
                                                      const float* __restrict__ aw,
                                                      const unsigned* __restrict__ gmax,
                                                      float* __restrict__ out) {
    const int t    = threadIdx.x;
    const int lane = t & 63;
    const int g    = lane >> 3;
    const int sl   = lane & 7;
    const int node = blockIdx.x * 32 + (t >> 6) * 8 + g;

    const int lo = row_ptr[node];
    const int hi = row_ptr[node + 1];

    const uint2 q = *(const uint2*)&Q[(size_t)node * OUT_DIM + sl * 8];
    float acc[8] = {0.f,0.f,0.f,0.f,0.f,0.f,0.f,0.f};

    int  e1 = lo + 1;
    bool a0 = lo < hi, a1 = e1 < hi;
    {
        int d0 = dst[a0 ? lo : 0];
        int d1 = dst[a1 ? e1 : 0];
        uint2 x0 = *(const uint2*)&Q[(size_t)d0 * OUT_DIM + sl * 8];
        uint2 x1 = *(const uint2*)&Q[(size_t)d1 * OUT_DIM + sl * 8];

        while (__any(a0)) {
            const int  e2 = e1 + 1;
            const bool a2 = e2 < hi;
            const int  d2 = dst[a2 ? e2 : 0];
            const uint2 x2 = *(const uint2*)&Q[(size_t)d2 * OUT_DIM + sl * 8];

            int p = dot4i8(q.x, x0.x, 0);
            p     = dot4i8(q.y, x0.y, p);
            p += __shfl_xor(p, 1);
            p += __shfl_xor(p, 2);
            p += __shfl_xor(p, 4);
            const float pf = a0 ? (float)p : 0.f;
            const int32_t wx = (int32_t)x0.x, wy = (int32_t)x0.y;
            acc[0] = fmaf(pf, (float)((wx << 24) >> 24), acc[0]);
            acc[1] = fmaf(pf, (float)((wx << 16) >> 24), acc[1]);
            acc[2] = fmaf(pf, (float)((wx <<  8) >> 24), acc[2]);
            acc[3] = fmaf(pf, (float)( wx        >> 24), acc[3]);
            acc[4] = fmaf(pf, (float)((wy << 24) >> 24), acc[4]);
            acc[5] = fmaf(pf, (float)((wy << 16) >> 24), acc[5]);
            acc[6] = fmaf(pf, (float)((wy <<  8) >> 24), acc[6]);
            acc[7] = fmaf(pf, (float)( wy        >> 24), acc[7]);

            a0 = a1; x0 = x1;
            a1 = a2; x1 = x2; e1 = e2;
        }
    }

    const float gm = __uint_as_float(*gmax);
    const float s  = gm * (1.f / 127.f);
    const float k  = s * s * s * aw[0];
    float* o = &out[(size_t)node * OUT_DIM + sl * 8];
    *(float4*)&o[0] = make_float4(acc[0]*k, acc[1]*k, acc[2]*k, acc[3]*k);
    *(float4*)&o[4] = make_float4(acc[4]*k, acc[5]*k, acc[6]*k, acc[7]*k);
}

// ---------------------------------------------------------------------------
// Fallback f16 edge kernel (used when ws too small for Q): R5 version.
// ---------------------------------------------------------------------------
__global__ __launch_bounds__(256, 8) void agnn_edge(const _Float16* __restrict__ XPh,
                                                    const int* __restrict__ row_ptr,
                                                    const int* __restrict__ dst,
                                                    const float* __restrict__ aw,
                                                    float* __restrict__ out) {
    const int t    = threadIdx.x;
    const int lane = t & 63;
    const int g    = lane >> 3;
    const int sl   = lane & 7;
    const int node = blockIdx.x * 32 + (t >> 6) * 8 + g;

    const int lo = row_ptr[node];
    const int hi = row_ptr[node + 1];

    const uint4 q = *(const uint4*)&XPh[(size_t)node * OUT_DIM + sl * 8];
    float acc[8] = {0.f,0.f,0.f,0.f,0.f,0.f,0.f,0.f};

    int  e   = lo;
    bool act = e < hi;
    int  d   = dst[act ? e : 0];
    uint4 xd = *(const uint4*)&XPh[(size_t)d * OUT_DIM + sl * 8];

    while (true) {
        const int  en   = e + 1;
        const bool actn = en < hi;
        const int  dn   = dst[actn ? en : 0];
        const uint4 xdn = *(const uint4*)&XPh[(size_t)dn * OUT_DIM + sl * 8];

        float p = hdot8(q, xd, 0.f);
        p += __shfl_xor(p, 1);
        p += __shfl_xor(p, 2);
        p += __shfl_xor(p, 4);
        p = act ? p : 0.f;
        const h2 d0 = __builtin_bit_cast(h2, xd.x);
        const h2 d1 = __builtin_bit_cast(h2, xd.y);
        const h2 d2 = __builtin_bit_cast(h2, xd.z);
        const h2 d3 = __builtin_bit_cast(h2, xd.w);
        acc[0] = fmaf(p, (float)d0[0], acc[0]);
        acc[1] = fmaf(p, (float)d0[1], acc[1]);
        acc[2] = fmaf(p, (float)d1[0], acc[2]);
        acc[3] = fmaf(p, (float)d1[1], acc[3]);
        acc[4] = fmaf(p, (float)d2[0], acc[4]);
        acc[5] = fmaf(p, (float)d2[1], acc[5]);
        acc[6] = fmaf(p, (float)d3[0], acc[6]);
        acc[7] = fmaf(p, (float)d3[1], acc[7]);

        e = en; act = actn; xd = xdn;
        if (!__any(act)) break;
    }

    const float a = aw[0];
    float* o = &out[(size_t)node * OUT_DIM + sl * 8];
    *(float4*)&o[0] = make_float4(acc[0]*a, acc[1]*a, acc[2]*a, acc[3]*a);
    *(float4*)&o[4] = make_float4(acc[4]*a, acc[5]*a, acc[6]*a, acc[7]*a);
}

// ---------------------------------------------------------------------------
extern "C" void kernel_launch(void* const* d_in, const int* in_sizes, int n_in,
                              void* d_out, int out_size, void* d_ws, size_t ws_size,
                              hipStream_t stream) {
    const float* X   = (const float*)d_in[0];
    const float* W   = (const float*)d_in[1];
    const float* aw  = (const float*)d_in[2];
    const int*   src = (const int*)d_in[3];
    const int*   dst = (const int*)d_in[4];
    float* out = (float*)d_out;

    // ws layout (bytes):
    //   XPh     @ 0          12,800,000  (f16 N*64)
    //   row_ptr @ 12,800,000    400,004
    //   Wfrag   @ 13,200,016     16,384
    //   gmax    @ 13,216,400          4
    //   Q       @ 13,216,416  6,400,000   -> end 19,616,416
    _Float16* XPh     = (_Float16*)d_ws;
    int*      row_ptr = (int*)((char*)d_ws + 12800000);
    uint4*    Wfrag   = (uint4*)((char*)d_ws + 13200016);
    unsigned* gmax    = (unsigned*)((char*)d_ws + 13216400);
    uint8_t*  Q       = (uint8_t*)((char*)d_ws + 13216416);

    prep<<<N_EDGES / 256 + 4, 256, 0, stream>>>(src, W, row_ptr, Wfrag, gmax);
    gemm_xw<<<(N_NODES + 63) / 64, 256, 0, stream>>>(X, Wfrag, XPh, gmax, N_NODES);

    if (ws_size >= (size_t)19616416) {
        quantize<<<3125, 256, 0, stream>>>(XPh, gmax, (uint2*)Q);
        agnn_edge_q<<<N_NODES / 32, 256, 0, stream>>>(Q, row_ptr, dst, aw, gmax, out);
    } else {
        agnn_edge<<<N_NODES / 32, 256, 0, stream>>>(XPh, row_ptr, dst, aw, out);
    }
}

// Round 7
// 56.833 us; speedup vs baseline: 3.5516x; 3.5516x over previous
//
#include <hip/hip_runtime.h>
#include <stdint.h>

#define N_NODES 100000
#define N_EDGES 1600000
#define IN_DIM 128
#define OUT_DIM 64

typedef __bf16    bf16x8 __attribute__((ext_vector_type(8)));
typedef float     f32x4  __attribute__((ext_vector_type(4)));
typedef _Float16  h2     __attribute__((ext_vector_type(2)));

__device__ __forceinline__ uint16_t f2bf(float f) {   // RNE
    uint32_t u = __float_as_uint(f);
    return (uint16_t)((u + 0x7fffu + ((u >> 16) & 1u)) >> 16);
}
__device__ __forceinline__ int dot4i8(uint32_t a, uint32_t b, int c) {
#if __has_builtin(__builtin_amdgcn_sdot4)
    return __builtin_amdgcn_sdot4((int)a, (int)b, c, false);
#else
    #pragma unroll
    for (int k = 0; k < 4; ++k)
        c += (int)(int8_t)(a >> (8 * k)) * (int)(int8_t)(b >> (8 * k));
    return c;
#endif
}
__device__ __forceinline__ float hdot8(uint4 a, uint4 b, float c) {
#if __has_builtin(__builtin_amdgcn_fdot2)
    c = __builtin_amdgcn_fdot2(__builtin_bit_cast(h2, a.x), __builtin_bit_cast(h2, b.x), c, false);
    c = __builtin_amdgcn_fdot2(__builtin_bit_cast(h2, a.y), __builtin_bit_cast(h2, b.y), c, false);
    c = __builtin_amdgcn_fdot2(__builtin_bit_cast(h2, a.z), __builtin_bit_cast(h2, b.z), c, false);
    c = __builtin_amdgcn_fdot2(__builtin_bit_cast(h2, a.w), __builtin_bit_cast(h2, b.w), c, false);
#else
    const h2 qa[4] = {__builtin_bit_cast(h2,a.x),__builtin_bit_cast(h2,a.y),
                      __builtin_bit_cast(h2,a.z),__builtin_bit_cast(h2,a.w)};
    const h2 qb[4] = {__builtin_bit_cast(h2,b.x),__builtin_bit_cast(h2,b.y),
                      __builtin_bit_cast(h2,b.z),__builtin_bit_cast(h2,b.w)};
    #pragma unroll
    for (int i = 0; i < 4; ++i) {
        c = fmaf((float)qa[i][0], (float)qb[i][0], c);
        c = fmaf((float)qa[i][1], (float)qb[i][1], c);
    }
#endif
    return c;
}

// ---------------------------------------------------------------------------
// prep: blocks [0,6250) build row_ptr from sorted edge_src (O(N+E));
//       blocks [6250,6254) pack W into per-lane MFMA B-fragments.
// ---------------------------------------------------------------------------
__global__ __launch_bounds__(256) void prep(const int* __restrict__ src,
                                            const float* __restrict__ W,
                                            int* __restrict__ row_ptr,
                                            uint4* __restrict__ Wfrag) {
    const int b = blockIdx.x;
    if (b < N_EDGES / 256) {
        int e = b * 256 + threadIdx.x;
        int s = src[e];
        if (e == 0) {
            for (int i = 0; i <= s; ++i) row_ptr[i] = 0;
        } else {
            int sp = src[e - 1];
            for (int i = sp + 1; i <= s; ++i) row_ptr[i] = e;
        }
        if (e == N_EDGES - 1) {
            for (int i = s + 1; i <= N_NODES; ++i) row_ptr[i] = N_EDGES;
        }
    } else {
        int item = (b - N_EDGES / 256) * 256 + threadIdx.x;   // 0..1023
        if (item < 1024) {
            int f = item >> 6, lane = item & 63;
            int ct = f >> 2, ks = f & 3;
            int col = ct * 16 + (lane & 15);
            int kb  = ks * 32 + (lane >> 4) * 8;
            uint32_t u[4];
            #pragma unroll
            for (int j = 0; j < 4; ++j) {
                uint32_t lo = f2bf(W[(kb + 2 * j)     * OUT_DIM + col]);
                uint32_t hi = f2bf(W[(kb + 2 * j + 1) * OUT_DIM + col]);
                u[j] = lo | (hi << 16);
            }
            Wfrag[f * 64 + lane] = make_uint4(u[0], u[1], u[2], u[3]);
        }
    }
}

// ---------------------------------------------------------------------------
// GEMM: XPh = f16(X @ W) via mfma_f32_16x16x32_bf16. Per-block max|acc| goes
// to blockmax[blockIdx] via LDS reduce + plain store (NO single-address
// atomics — R6 showed they serialize ~15x).
// ---------------------------------------------------------------------------
__global__ __launch_bounds__(256) void gemm_xw(const float* __restrict__ X,
                                               const uint4* __restrict__ Wfrag,
                                               _Float16* __restrict__ XPh,
                                               float* __restrict__ blockmax,
                                               int nRows) {
    __shared__ float wmax[4];
    const int t = threadIdx.x;
    const int lane = t & 63;

    bf16x8 bfr[16];
    #pragma unroll
    for (int f = 0; f < 16; ++f)
        bfr[f] = __builtin_bit_cast(bf16x8, Wfrag[f * 64 + lane]);

    const int rowBase = blockIdx.x * 64 + (t >> 6) * 16;
    const int r  = rowBase + (lane & 15);
    const int kb = (lane >> 4) * 8;
    const bool inb = r < nRows;

    f32x4 acc[4] = {{0,0,0,0},{0,0,0,0},{0,0,0,0},{0,0,0,0}};

    #pragma unroll
    for (int ks = 0; ks < 4; ++ks) {
        float4 x0 = make_float4(0.f,0.f,0.f,0.f), x1 = x0;
        if (inb) {
            const float* p = &X[(size_t)r * IN_DIM + ks * 32 + kb];
            x0 = *(const float4*)&p[0];
            x1 = *(const float4*)&p[4];
        }
        bf16x8 a;
        a[0]=(__bf16)x0.x; a[1]=(__bf16)x0.y; a[2]=(__bf16)x0.z; a[3]=(__bf16)x0.w;
        a[4]=(__bf16)x1.x; a[5]=(__bf16)x1.y; a[6]=(__bf16)x1.z; a[7]=(__bf16)x1.w;
        #pragma unroll
        for (int ct = 0; ct < 4; ++ct)
            acc[ct] = __builtin_amdgcn_mfma_f32_16x16x32_bf16(a, bfr[ct * 4 + ks], acc[ct], 0, 0, 0);
    }

    const int orow = rowBase + (lane >> 4) * 4;
    const int ocol = lane & 15;
    float m = 0.f;
    #pragma unroll
    for (int ct = 0; ct < 4; ++ct) {
        #pragma unroll
        for (int rr = 0; rr < 4; ++rr) {
            int gr = orow + rr;
            if (gr < nRows) XPh[(size_t)gr * OUT_DIM + ct * 16 + ocol] = (_Float16)acc[ct][rr];
            m = fmaxf(m, fabsf(acc[ct][rr]));
        }
    }
    #pragma unroll
    for (int off = 1; off < 64; off <<= 1) m = fmaxf(m, __shfl_xor(m, off));
    if (lane == 0) wmax[t >> 6] = m;
    __syncthreads();
    if (t == 0)
        blockmax[blockIdx.x] = fmaxf(fmaxf(wmax[0], wmax[1]), fmaxf(wmax[2], wmax[3]));
}

// ---------------------------------------------------------------------------
// reduce_gmax: one block reduces blockmax[n] -> *gmax (plain float store).
// ---------------------------------------------------------------------------
__global__ __launch_bounds__(256) void reduce_gmax(const float* __restrict__ blockmax,
                                                   int n, float* __restrict__ gmax) {
    __shared__ float wmax[4];
    const int t = threadIdx.x;
    float m = 0.f;
    for (int i = t; i < n; i += 256) m = fmaxf(m, blockmax[i]);
    #pragma unroll
    for (int off = 1; off < 64; off <<= 1) m = fmaxf(m, __shfl_xor(m, off));
    if ((t & 63) == 0) wmax[t >> 6] = m;
    __syncthreads();
    if (t == 0)
        *gmax = fmaxf(fmaxf(wmax[0], wmax[1]), fmaxf(wmax[2], wmax[3]));
}

// ---------------------------------------------------------------------------
// quantize: Q[i] = int8(clamp(rint(XPh[i] * 127/gmax), -127, 127)).
// Clamp guards f16 values that rounded above the f32-derived gmax.
// ---------------------------------------------------------------------------
__global__ __launch_bounds__(256) void quantize(const _Float16* __restrict__ XPh,
                                                const float* __restrict__ gmax,
                                                uint2* __restrict__ Q) {
    const int i = blockIdx.x * 256 + threadIdx.x;        // 800000 threads
    const float gm = *gmax;
    const float inv = gm > 0.f ? 127.f / gm : 0.f;
    uint4 h = ((const uint4*)XPh)[i];
    uint32_t w[2];
    #pragma unroll
    for (int half = 0; half < 2; ++half) {
        uint32_t res = 0;
        #pragma unroll
        for (int j = 0; j < 2; ++j) {
            uint32_t hw = half == 0 ? (j == 0 ? h.x : h.y) : (j == 0 ? h.z : h.w);
            h2 p = __builtin_bit_cast(h2, hw);
            int v0 = (int)rintf((float)p[0] * inv);
            int v1 = (int)rintf((float)p[1] * inv);
            v0 = min(127, max(-127, v0));
            v1 = min(127, max(-127, v1));
            res |= ((uint32_t)(uint8_t)(int8_t)v0) << (j * 16);
            res |= ((uint32_t)(uint8_t)(int8_t)v1) << (j * 16 + 8);
        }
        w[half] = res;
    }
    Q[i] = make_uint2(w[0], w[1]);
}

// ---------------------------------------------------------------------------
// Edge kernel (int8): one NODE per 8-lane group; row = 64B = one cache line.
// Per 8-edge chunk: ONE coalesced dst load per group (8 indices, distributed
// via shfl), then all 8 row-gathers issued back-to-back (8x64B in flight per
// group), then compute. Next chunk's indices prefetched during compute.
// Final scale (gmax/127)^3 * aw applied once.
// ---------------------------------------------------------------------------
__global__ __launch_bounds__(256, 8) void agnn_edge_q(const uint8_t* __restrict__ Q,
                                                      const int* __restrict__ row_ptr,
                                                      const int* __restrict__ dst,
                                                      const float* __restrict__ aw,
                                                      const float* __restrict__ gmax,
                                                      float* __restrict__ out) {
    const int t    = threadIdx.x;
    const int lane = t & 63;
    const int g    = lane >> 3;
    const int sl   = lane & 7;
    const int node = blockIdx.x * 32 + (t >> 6) * 8 + g;

    const int lo = row_ptr[node];
    const int hi = row_ptr[node + 1];

    const uint2 q = *(const uint2*)&Q[(size_t)node * OUT_DIM + sl * 8];
    float acc[8] = {0.f,0.f,0.f,0.f,0.f,0.f,0.f,0.f};

    // clamped edge index for this lane's slot of a chunk
    auto clampe = [&](int ee) {
        ee = min(ee, hi - 1);
        ee = max(ee, 0);
        return min(ee, N_EDGES - 1);
    };

    int base = lo;
    int myd  = dst[clampe(base + sl)];

    while (__any(base < hi)) {
        const int mydn = dst[clampe(base + 8 + sl)];   // prefetch next chunk

        uint2 x[8];
        #pragma unroll
        for (int j = 0; j < 8; ++j) {
            const int dj = __shfl(myd, g * 8 + j);
            x[j] = *(const uint2*)&Q[(size_t)dj * OUT_DIM + sl * 8];
        }
        #pragma unroll
        for (int j = 0; j < 8; ++j) {
            int p = dot4i8(q.x, x[j].x, 0);
            p     = dot4i8(q.y, x[j].y, p);
            p += __shfl_xor(p, 1);
            p += __shfl_xor(p, 2);
            p += __shfl_xor(p, 4);
            const float pf = (base + j < hi) ? (float)p : 0.f;
            const int32_t wx = (int32_t)x[j].x, wy = (int32_t)x[j].y;
            acc[0] = fmaf(pf, (float)((wx << 24) >> 24), acc[0]);
            acc[1] = fmaf(pf, (float)((wx << 16) >> 24), acc[1]);
            acc[2] = fmaf(pf, (float)((wx <<  8) >> 24), acc[2]);
            acc[3] = fmaf(pf, (float)( wx        >> 24), acc[3]);
            acc[4] = fmaf(pf, (float)((wy << 24) >> 24), acc[4]);
            acc[5] = fmaf(pf, (float)((wy << 16) >> 24), acc[5]);
            acc[6] = fmaf(pf, (float)((wy <<  8) >> 24), acc[6]);
            acc[7] = fmaf(pf, (float)( wy        >> 24), acc[7]);
        }
        base += 8;
        myd = mydn;
    }

    const float gm = *gmax;
    const float s  = gm * (1.f / 127.f);
    const float k  = s * s * s * aw[0];
    float* o = &out[(size_t)node * OUT_DIM + sl * 8];
    *(float4*)&o[0] = make_float4(acc[0]*k, acc[1]*k, acc[2]*k, acc[3]*k);
    *(float4*)&o[4] = make_float4(acc[4]*k, acc[5]*k, acc[6]*k, acc[7]*k);
}

// ---------------------------------------------------------------------------
// Fallback f16 edge kernel (used when ws too small for Q).
// ---------------------------------------------------------------------------
__global__ __launch_bounds__(256, 8) void agnn_edge(const _Float16* __restrict__ XPh,
                                                    const int* __restrict__ row_ptr,
                                                    const int* __restrict__ dst,
                                                    const float* __restrict__ aw,
                                                    float* __restrict__ out) {
    const int t    = threadIdx.x;
    const int lane = t & 63;
    const int g    = lane >> 3;
    const int sl   = lane & 7;
    const int node = blockIdx.x * 32 + (t >> 6) * 8 + g;

    const int lo = row_ptr[node];
    const int hi = row_ptr[node + 1];

    const uint4 q = *(const uint4*)&XPh[(size_t)node * OUT_DIM + sl * 8];
    float acc[8] = {0.f,0.f,0.f,0.f,0.f,0.f,0.f,0.f};

    int  e   = lo;
    bool act = e < hi;
    int  d   = dst[act ? e : 0];
    uint4 xd = *(const uint4*)&XPh[(size_t)d * OUT_DIM + sl * 8];

    while (true) {
        const int  en   = e + 1;
        const bool actn = en < hi;
        const int  dn   = dst[actn ? en : 0];
        const uint4 xdn = *(const uint4*)&XPh[(size_t)dn * OUT_DIM + sl * 8];

        float p = hdot8(q, xd, 0.f);
        p += __shfl_xor(p, 1);
        p += __shfl_xor(p, 2);
        p += __shfl_xor(p, 4);
        p = act ? p : 0.f;
        const h2 d0 = __builtin_bit_cast(h2, xd.x);
        const h2 d1 = __builtin_bit_cast(h2, xd.y);
        const h2 d2 = __builtin_bit_cast(h2, xd.z);
        const h2 d3 = __builtin_bit_cast(h2, xd.w);
        acc[0] = fmaf(p, (float)d0[0], acc[0]);
        acc[1] = fmaf(p, (float)d0[1], acc[1]);
        acc[2] = fmaf(p, (float)d1[0], acc[2]);
        acc[3] = fmaf(p, (float)d1[1], acc[3]);
        acc[4] = fmaf(p, (float)d2[0], acc[4]);
        acc[5] = fmaf(p, (float)d2[1], acc[5]);
        acc[6] = fmaf(p, (float)d3[0], acc[6]);
        acc[7] = fmaf(p, (float)d3[1], acc[7]);

        e = en; act = actn; xd = xdn;
        if (!__any(act)) break;
    }

    const float a = aw[0];
    float* o = &out[(size_t)node * OUT_DIM + sl * 8];
    *(float4*)&o[0] = make_float4(acc[0]*a, acc[1]*a, acc[2]*a, acc[3]*a);
    *(float4*)&o[4] = make_float4(acc[4]*a, acc[5]*a, acc[6]*a, acc[7]*a);
}

// ---------------------------------------------------------------------------
extern "C" void kernel_launch(void* const* d_in, const int* in_sizes, int n_in,
                              void* d_out, int out_size, void* d_ws, size_t ws_size,
                              hipStream_t stream) {
    const float* X   = (const float*)d_in[0];
    const float* W   = (const float*)d_in[1];
    const float* aw  = (const float*)d_in[2];
    const int*   src = (const int*)d_in[3];
    const int*   dst = (const int*)d_in[4];
    float* out = (float*)d_out;

    // ws layout (bytes):
    //   XPh      @ 0          12,800,000  (f16 N*64)
    //   row_ptr  @ 12,800,000    400,004
    //   Wfrag    @ 13,200,016     16,384
    //   gmax     @ 13,216,400          4
    //   blockmax @ 13,216,404      6,252  (1563 f32)
    //   Q        @ 13,222,656  6,400,000  -> end 19,622,656
    _Float16* XPh      = (_Float16*)d_ws;
    int*      row_ptr  = (int*)((char*)d_ws + 12800000);
    uint4*    Wfrag    = (uint4*)((char*)d_ws + 13200016);
    float*    gmax     = (float*)((char*)d_ws + 13216400);
    float*    blockmax = (float*)((char*)d_ws + 13216404);
    uint8_t*  Q        = (uint8_t*)((char*)d_ws + 13222656);

    const int nGemmBlocks = (N_NODES + 63) / 64;   // 1563

    prep<<<N_EDGES / 256 + 4, 256, 0, stream>>>(src, W, row_ptr, Wfrag);
    gemm_xw<<<nGemmBlocks, 256, 0, stream>>>(X, Wfrag, XPh, blockmax, N_NODES);

    if (ws_size >= (size_t)19622656) {
        reduce_gmax<<<1, 256, 0, stream>>>(blockmax, nGemmBlocks, gmax);
        quantize<<<3125, 256, 0, stream>>>(XPh, gmax, (uint2*)Q);
        agnn_edge_q<<<N_NODES / 32, 256, 0, stream>>>(Q, row_ptr, dst, aw, gmax, out);
    } else {
        agnn_edge<<<N_NODES / 32, 256, 0, stream>>>(XPh, row_ptr, dst, aw, out);
    }
}